// Round 14
// baseline (311.874 us; speedup 1.0000x reference)
//
#include <hip/hip_runtime.h>
#include <math.h>

#define N_NODES 650
#define DIM     512
#define E_RAW   150000
#define E_TOT   150650
#define WK      672              // padded row length for dense attention matrix
#define ZF      8                // feat split-K slices (K=512, 64 each)
#define ZA      6                // agg split-K slices  (K=672, 112 each)
#define LP      656              // logit-partial row stride

// =============== feature GEMM (split-K z=8), plain stores + logit partials ===============
// P[z][r,c] = (A @ B)[r,c] over k in [z*64,(z+1)*64).
// a_mode 1: rows<400 from A (x_s), >=400 from Axt (x_t).
// a_mode 3: A = relu( (sum_z Qin[z]) * inv_rs + bias_prev )  (layer-1 output, fused)
__global__ __launch_bounds__(256)
void k_feat(const float* __restrict__ A, const float* __restrict__ Axt,
            const float* __restrict__ B,
            const float* __restrict__ asrc, const float* __restrict__ adst,
            const float* __restrict__ Qin, const float* __restrict__ rsp,
            const float* __restrict__ bp,
            float* __restrict__ P, float* __restrict__ alsp, float* __restrict__ aldp,
            int a_mode) {
    __shared__ float Ast[16][68];   // transposed A tile (stride 68)
    __shared__ float Bs[16][64];
    int t = threadIdx.x;
    int tx4 = (t & 15) * 4, ty4 = (t >> 4) * 4;
    int row0 = blockIdx.y * 64, col0 = blockIdx.x * 64;
    int z = blockIdx.z;
    int kbase = z * 64;
    int ar = t >> 2, ak = (t & 3) * 4;     // A staging: 64 rows x 16 k
    int bk = t >> 4, bn = (t & 15) * 4;    // B staging: 16 k x 64 cols
    float acc[4][4] = {};
    const size_t S = (size_t)N_NODES * DIM;

    for (int kb = kbase; kb < kbase + 64; kb += 16) {
        {
            int gr = row0 + ar;
            float4 v = make_float4(0.f, 0.f, 0.f, 0.f);
            if (gr < N_NODES) {
                if (a_mode == 1) {
                    const float* rowp = (gr < 400) ? A + (size_t)gr * DIM
                                                   : Axt + (size_t)(gr - 400) * DIM;
                    v = *(const float4*)(rowp + kb + ak);
                } else {
                    size_t off = (size_t)gr * DIM + kb + ak;
                    float4 q = *(const float4*)(Qin + off);
                    #pragma unroll
                    for (int zz = 1; zz < ZA; zz++) {
                        float4 q2 = *(const float4*)(Qin + (size_t)zz * S + off);
                        q.x += q2.x; q.y += q2.y; q.z += q2.z; q.w += q2.w;
                    }
                    float inv = 1.f / (rsp[gr] + 1e-16f);
                    float4 bb = *(const float4*)&bp[kb + ak];
                    v.x = fmaxf(fmaf(q.x, inv, bb.x), 0.f);
                    v.y = fmaxf(fmaf(q.y, inv, bb.y), 0.f);
                    v.z = fmaxf(fmaf(q.z, inv, bb.z), 0.f);
                    v.w = fmaxf(fmaf(q.w, inv, bb.w), 0.f);
                }
            }
            Ast[ak + 0][ar] = v.x; Ast[ak + 1][ar] = v.y;
            Ast[ak + 2][ar] = v.z; Ast[ak + 3][ar] = v.w;
        }
        *(float4*)&Bs[bk][bn] = *(const float4*)&B[(size_t)(kb + bk) * DIM + col0 + bn];
        __syncthreads();
        #pragma unroll
        for (int kk = 0; kk < 16; kk++) {
            float4 a = *(const float4*)&Ast[kk][ty4];
            float4 b = *(const float4*)&Bs[kk][tx4];
            acc[0][0] += a.x*b.x; acc[0][1] += a.x*b.y; acc[0][2] += a.x*b.z; acc[0][3] += a.x*b.w;
            acc[1][0] += a.y*b.x; acc[1][1] += a.y*b.y; acc[1][2] += a.y*b.z; acc[1][3] += a.y*b.w;
            acc[2][0] += a.z*b.x; acc[2][1] += a.z*b.y; acc[2][2] += a.z*b.z; acc[2][3] += a.z*b.w;
            acc[3][0] += a.w*b.x; acc[3][1] += a.w*b.y; acc[3][2] += a.w*b.z; acc[3][3] += a.w*b.w;
        }
        __syncthreads();
    }

    // epilogue: plain P store + one-writer logit partial store (no atomics)
    float4 as4 = *(const float4*)&asrc[col0 + tx4];
    float4 ad4 = *(const float4*)&adst[col0 + tx4];
    float* Pz = P + (size_t)z * S;
    int slice = z * 8 + blockIdx.x;             // 64 slices
    #pragma unroll
    for (int i = 0; i < 4; i++) {
        int gr = row0 + ty4 + i;
        float sa = acc[i][0]*as4.x + acc[i][1]*as4.y + acc[i][2]*as4.z + acc[i][3]*as4.w;
        float sd = acc[i][0]*ad4.x + acc[i][1]*ad4.y + acc[i][2]*ad4.z + acc[i][3]*ad4.w;
        #pragma unroll
        for (int o = 8; o > 0; o >>= 1) {
            sa += __shfl_down(sa, o, 16);
            sd += __shfl_down(sd, o, 16);
        }
        if (gr < N_NODES) {
            *(float4*)&Pz[(size_t)gr * DIM + col0 + tx4] =
                make_float4(acc[i][0], acc[i][1], acc[i][2], acc[i][3]);
            if ((t & 15) == 0) {
                alsp[slice * LP + gr] = sa;
                aldp[slice * LP + gr] = sd;
            }
        }
    }
}

// =============== build: logit-reduce (LDS) + edges -> W + h-reduce ===============
__global__ __launch_bounds__(256)
void k_build(const int* __restrict__ ei,
             const float* __restrict__ alsp, const float* __restrict__ aldp,
             const float* __restrict__ P, float* __restrict__ h,
             float* __restrict__ W, float* __restrict__ rs) {
    __shared__ float als[N_NODES], ald[N_NODES], lrs[N_NODES];
    int t = threadIdx.x;
    const int stride = gridDim.x * 256;

    // phase 1: per-block reduce of the 64 logit partial slices (coalesced across lanes)
    for (int l = t; l < N_NODES; l += 256) {
        float sa = 0.f, sd = 0.f;
        #pragma unroll
        for (int j = 0; j < 64; j++) {
            sa += alsp[j * LP + l];
            sd += aldp[j * LP + l];
        }
        als[l] = sa; ald[l] = sd; lrs[l] = 0.f;
    }
    __syncthreads();

    // phase 2: edges -> W (spread atomics), lrs (LDS atomics)
    for (int i = blockIdx.x * 256 + t; i < E_TOT; i += stride) {
        int s, d;
        if (i < E_RAW) { s = ei[i]; d = ei[E_RAW + i]; }
        else           { s = d = i - E_RAW; }
        float e = als[s] + ald[d];
        e = e > 0.f ? e : 0.2f * e;
        float ex = __expf(e);
        atomicAdd(&W[(size_t)d * WK + s], ex);
        atomicAdd(&lrs[d], ex);
    }
    __syncthreads();
    for (int l = t; l < N_NODES; l += 256)
        if (lrs[l] != 0.f) atomicAdd(&rs[l], lrs[l]);

    // phase 3: h = sum_z P[z]  (grid-strided float4, plain stores)
    const int n4 = N_NODES * DIM / 4;           // 83200
    const size_t S4 = (size_t)N_NODES * DIM / 4;
    const float4* P4 = (const float4*)P;
    float4* h4 = (float4*)h;
    for (int i = blockIdx.x * 256 + t; i < n4; i += stride) {
        float4 a = P4[i];
        #pragma unroll
        for (int zz = 1; zz < ZF; zz++) {
            float4 b = P4[(size_t)zz * S4 + i];
            a.x += b.x; a.y += b.y; a.z += b.z; a.w += b.w;
        }
        h4[i] = a;
    }
}

// =============== agg GEMM (split-K z=6): Q[z][d,c] = partial (W @ h), plain stores ===============
__global__ __launch_bounds__(256)
void k_agg(const float* __restrict__ W, const float* __restrict__ hbuf,
           float* __restrict__ Q) {
    __shared__ float Ast[16][68];
    __shared__ float Bs[16][64];
    int t = threadIdx.x;
    int tx4 = (t & 15) * 4, ty4 = (t >> 4) * 4;
    int row0 = blockIdx.y * 64, col0 = blockIdx.x * 64;
    int kbase = blockIdx.z * 112;
    int ar = t >> 2, ak = (t & 3) * 4;
    int bk = t >> 4, bn = (t & 15) * 4;
    float acc[4][4] = {};

    for (int kb = kbase; kb < kbase + 112; kb += 16) {
        {
            int gr = row0 + ar;
            float4 v = make_float4(0.f, 0.f, 0.f, 0.f);
            if (gr < N_NODES)
                v = *(const float4*)(W + (size_t)gr * WK + kb + ak);
            Ast[ak + 0][ar] = v.x; Ast[ak + 1][ar] = v.y;
            Ast[ak + 2][ar] = v.z; Ast[ak + 3][ar] = v.w;
        }
        *(float4*)&Bs[bk][bn] = *(const float4*)&hbuf[(size_t)(kb + bk) * DIM + col0 + bn];
        __syncthreads();
        #pragma unroll
        for (int kk = 0; kk < 16; kk++) {
            float4 a = *(const float4*)&Ast[kk][ty4];
            float4 b = *(const float4*)&Bs[kk][tx4];
            acc[0][0] += a.x*b.x; acc[0][1] += a.x*b.y; acc[0][2] += a.x*b.z; acc[0][3] += a.x*b.w;
            acc[1][0] += a.y*b.x; acc[1][1] += a.y*b.y; acc[1][2] += a.y*b.z; acc[1][3] += a.y*b.w;
            acc[2][0] += a.z*b.x; acc[2][1] += a.z*b.y; acc[2][2] += a.z*b.z; acc[2][3] += a.z*b.w;
            acc[3][0] += a.w*b.x; acc[3][1] += a.w*b.y; acc[3][2] += a.w*b.z; acc[3][3] += a.w*b.w;
        }
        __syncthreads();
    }

    float* Qz = Q + (size_t)blockIdx.z * (N_NODES * DIM);
    #pragma unroll
    for (int i = 0; i < 4; i++) {
        int gr = row0 + ty4 + i;
        if (gr < N_NODES)
            *(float4*)&Qz[(size_t)gr * DIM + col0 + tx4] =
                make_float4(acc[i][0], acc[i][1], acc[i][2], acc[i][3]);
    }
}

// =============== final: act(sum_z Q[z]) viewed as (512,650) @ fc_w + fc_b -> sigmoid ===============
__global__ void k_final(const float* __restrict__ Q, const float* __restrict__ rs,
                        const float* __restrict__ bias,
                        const float* __restrict__ fcw, const float* __restrict__ fcb,
                        float* __restrict__ out) {
    int b = blockIdx.x * 4 + (threadIdx.x >> 6);
    int lane = threadIdx.x & 63;
    if (b >= 512) return;
    const size_t S = (size_t)N_NODES * DIM;
    float s = 0.f;
    for (int i = lane; i < N_NODES; i += 64) {
        int j = b * N_NODES + i;
        float q = Q[j];
        #pragma unroll
        for (int zz = 1; zz < ZA; zz++) q += Q[(size_t)zz * S + j];
        int r = j >> 9, c = j & 511;           // storage is (650, 512) row-major
        float v = fmaf(q, 1.f / (rs[r] + 1e-16f), bias[c]);
        v = v > 0.f ? v : 0.01f * v;
        s += v * fcw[i];
    }
    #pragma unroll
    for (int o = 32; o > 0; o >>= 1) s += __shfl_down(s, o);
    if (lane == 0) out[b] = 1.f / (1.f + expf(-(s + fcb[0])));
}

extern "C" void kernel_launch(void* const* d_in, const int* in_sizes, int n_in,
                              void* d_out, int out_size, void* d_ws, size_t ws_size,
                              hipStream_t stream) {
    const float* x_s   = (const float*)d_in[0];
    const float* x_t   = (const float*)d_in[1];
    const int*   ei    = (const int*)d_in[2];
    const float* W1    = (const float*)d_in[5];
    const float* asrc1 = (const float*)d_in[6];
    const float* adst1 = (const float*)d_in[7];
    const float* b1    = (const float*)d_in[8];
    const float* W4    = (const float*)d_in[9];
    const float* asrc4 = (const float*)d_in[10];
    const float* adst4 = (const float*)d_in[11];
    const float* b4    = (const float*)d_in[12];
    const float* fcw   = (const float*)d_in[13];
    const float* fcb   = (const float*)d_in[14];
    float* out = (float*)d_out;

    // layout: [ P (8S) | Q (6S) | alsp | aldp | hbuf (672x512) | W1d | W2d | rs1 rs2 ]
    // zero span: hbuf pad rows .. rs2 end (contiguous, 3.5 MB)
    const size_t S = (size_t)N_NODES * DIM;          // 332800
    float* ws   = (float*)d_ws;
    float* P    = ws;                                // 8*S
    float* Q    = P + (size_t)ZF * S;                // 6*S
    float* alsp = Q + (size_t)ZA * S;                // 64*656
    float* aldp = alsp + 64 * LP;                    // 64*656
    float* hbuf = aldp + 64 * LP;                    // 672*512
    float* W1d  = hbuf + (size_t)WK * DIM;           // 650*672
    float* W2d  = W1d + (size_t)N_NODES * WK;        // 650*672
    float* rs1  = W2d + (size_t)N_NODES * WK;        // 650
    float* rs2  = rs1 + N_NODES;                     // 650

    float* zbeg = hbuf + (size_t)N_NODES * DIM;
    size_t zbytes = (size_t)((WK - N_NODES) * DIM    // hbuf pad rows (22*512)
                           + 2 * N_NODES * WK        // W1d, W2d
                           + 2 * N_NODES)            // rs1, rs2
                    * sizeof(float);
    hipMemsetAsync(zbeg, 0, zbytes, stream);

    dim3 gF(DIM / 64, (N_NODES + 63) / 64, ZF);      // 8 x 11 x 8 = 704 blocks
    dim3 gA(DIM / 64, (N_NODES + 63) / 64, ZA);      // 8 x 11 x 6 = 528 blocks

    // ---- layer 1 ----
    k_feat<<<gF, 256, 0, stream>>>(x_s, x_t, W1, asrc1, adst1,
                                   nullptr, nullptr, nullptr,
                                   P, alsp, aldp, 1);
    k_build<<<128, 256, 0, stream>>>(ei, alsp, aldp, P, hbuf, W1d, rs1);
    k_agg<<<gA, 256, 0, stream>>>(W1d, hbuf, Q);

    // ---- layer 2 (layer-1 normalize/bias/relu fused into A-staging from Q) ----
    k_feat<<<gF, 256, 0, stream>>>(nullptr, nullptr, W4, asrc4, adst4,
                                   Q, rs1, b1,
                                   P, alsp, aldp, 3);
    k_build<<<128, 256, 0, stream>>>(ei, alsp, aldp, P, hbuf, W2d, rs2);
    k_agg<<<gA, 256, 0, stream>>>(W2d, hbuf, Q);

    // ---- final (layer-2 normalize/bias/leaky fused into load) ----
    k_final<<<128, 256, 0, stream>>>(Q, rs2, b4, fcw, fcb, out);
}

// Round 15
// 188.893 us; speedup vs baseline: 1.6511x; 1.6511x over previous
//
#include <hip/hip_runtime.h>
#include <math.h>

#define N_NODES 650
#define DIM     512
#define E_RAW   150000
#define E_TOT   150650
#define WK      672              // padded K for agg GEMM (W cols 650..671 stay zero)
#define ZF      8                // feat split-K slices (K=512, 64 each)
#define ZA      6                // agg split-K slices  (K=672, 112 each)
#define RSP     656              // rsp row stride

// =============== feature GEMM (split-K z=8), plain stores, row-interleaved P ===============
// P[(r*8+z)*512+c] = partial (A@B) over k in [z*64,(z+1)*64). Logit partial dots -> alsp/aldp.
// a_mode 1: rows<400 from A (x_s), >=400 from Axt (x_t).
// a_mode 3: A = relu( (sum_z Qin[r][z]) * inv_rs + bias_prev ), rs = sum_z rspp[z][r].
__global__ __launch_bounds__(256)
void k_feat(const float* __restrict__ A, const float* __restrict__ Axt,
            const float* __restrict__ B,
            const float* __restrict__ asrc, const float* __restrict__ adst,
            const float* __restrict__ Qin, const float* __restrict__ rspp,
            const float* __restrict__ bp,
            float* __restrict__ P, float* __restrict__ alsp, float* __restrict__ aldp,
            int a_mode) {
    __shared__ float Ast[16][68];
    __shared__ float Bs[16][64];
    int t = threadIdx.x;
    int tx4 = (t & 15) * 4, ty4 = (t >> 4) * 4;
    int row0 = blockIdx.y * 64, col0 = blockIdx.x * 64;
    int z = blockIdx.z;
    int kbase = z * 64;
    int ar = t >> 2, ak = (t & 3) * 4;
    int bk = t >> 4, bn = (t & 15) * 4;
    float acc[4][4] = {};
    int gr_a = row0 + ar;

    float inv = 0.f;                         // mode-3 normalizer, hoisted (gr_a fixed)
    if (a_mode == 3 && gr_a < N_NODES) {
        float r = 0.f;
        #pragma unroll
        for (int zz = 0; zz < ZA; zz++) r += rspp[zz * RSP + gr_a];
        inv = 1.f / (r + 1e-16f);
    }

    for (int kb = kbase; kb < kbase + 64; kb += 16) {
        {
            float4 v = make_float4(0.f, 0.f, 0.f, 0.f);
            if (gr_a < N_NODES) {
                if (a_mode == 1) {
                    const float* rowp = (gr_a < 400) ? A + (size_t)gr_a * DIM
                                                     : Axt + (size_t)(gr_a - 400) * DIM;
                    v = *(const float4*)(rowp + kb + ak);
                } else {
                    size_t rb = (size_t)gr_a * ZA * DIM + kb + ak;
                    float4 q = *(const float4*)(Qin + rb);
                    #pragma unroll
                    for (int zz = 1; zz < ZA; zz++) {
                        float4 q2 = *(const float4*)(Qin + rb + (size_t)zz * DIM);
                        q.x += q2.x; q.y += q2.y; q.z += q2.z; q.w += q2.w;
                    }
                    float4 bb = *(const float4*)&bp[kb + ak];
                    v.x = fmaxf(fmaf(q.x, inv, bb.x), 0.f);
                    v.y = fmaxf(fmaf(q.y, inv, bb.y), 0.f);
                    v.z = fmaxf(fmaf(q.z, inv, bb.z), 0.f);
                    v.w = fmaxf(fmaf(q.w, inv, bb.w), 0.f);
                }
            }
            Ast[ak + 0][ar] = v.x; Ast[ak + 1][ar] = v.y;
            Ast[ak + 2][ar] = v.z; Ast[ak + 3][ar] = v.w;
        }
        *(float4*)&Bs[bk][bn] = *(const float4*)&B[(size_t)(kb + bk) * DIM + col0 + bn];
        __syncthreads();
        #pragma unroll
        for (int kk = 0; kk < 16; kk++) {
            float4 a = *(const float4*)&Ast[kk][ty4];
            float4 b = *(const float4*)&Bs[kk][tx4];
            acc[0][0] += a.x*b.x; acc[0][1] += a.x*b.y; acc[0][2] += a.x*b.z; acc[0][3] += a.x*b.w;
            acc[1][0] += a.y*b.x; acc[1][1] += a.y*b.y; acc[1][2] += a.y*b.z; acc[1][3] += a.y*b.w;
            acc[2][0] += a.z*b.x; acc[2][1] += a.z*b.y; acc[2][2] += a.z*b.z; acc[2][3] += a.z*b.w;
            acc[3][0] += a.w*b.x; acc[3][1] += a.w*b.y; acc[3][2] += a.w*b.z; acc[3][3] += a.w*b.w;
        }
        __syncthreads();
    }

    // epilogue: plain interleaved-P store + one-writer logit partials (no atomics)
    float4 as4 = *(const float4*)&asrc[col0 + tx4];
    float4 ad4 = *(const float4*)&adst[col0 + tx4];
    int slice = z * 8 + blockIdx.x;              // 64 slices
    #pragma unroll
    for (int i = 0; i < 4; i++) {
        int gr = row0 + ty4 + i;
        float sa = acc[i][0]*as4.x + acc[i][1]*as4.y + acc[i][2]*as4.z + acc[i][3]*as4.w;
        float sd = acc[i][0]*ad4.x + acc[i][1]*ad4.y + acc[i][2]*ad4.z + acc[i][3]*ad4.w;
        #pragma unroll
        for (int o = 8; o > 0; o >>= 1) {
            sa += __shfl_down(sa, o, 16);
            sd += __shfl_down(sd, o, 16);
        }
        if (gr < N_NODES) {
            *(float4*)&P[((size_t)gr * ZF + z) * DIM + col0 + tx4] =
                make_float4(acc[i][0], acc[i][1], acc[i][2], acc[i][3]);
            if ((t & 15) == 0) {
                alsp[gr * 64 + slice] = sa;
                aldp[gr * 64 + slice] = sd;
            }
        }
    }
}

// =============== build: vectorized logit reduce + edge scatter -> W (spread atomics) ===============
__global__ __launch_bounds__(256)
void k_build(const int* __restrict__ ei,
             const float* __restrict__ alsp, const float* __restrict__ aldp,
             float* __restrict__ W) {
    __shared__ float als[N_NODES], ald[N_NODES];
    int t = threadIdx.x;
    for (int l = t; l < N_NODES; l += 256) {
        const float4* ap = (const float4*)(alsp + l * 64);
        const float4* dp = (const float4*)(aldp + l * 64);
        float sa = 0.f, sd = 0.f;
        #pragma unroll
        for (int j = 0; j < 16; j++) {
            float4 a = ap[j]; sa += a.x + a.y + a.z + a.w;
            float4 d = dp[j]; sd += d.x + d.y + d.z + d.w;
        }
        als[l] = sa; ald[l] = sd;
    }
    __syncthreads();
    const int stride = gridDim.x * 256;
    for (int i = blockIdx.x * 256 + t; i < E_TOT; i += stride) {
        int s, d;
        if (i < E_RAW) { s = ei[i]; d = ei[E_RAW + i]; }
        else           { s = d = i - E_RAW; }
        float e = als[s] + ald[d];
        e = e > 0.f ? e : 0.2f * e;
        atomicAdd(&W[(size_t)d * WK + s], __expf(e));
    }
}

// =============== agg GEMM (split-K z=6): B = sum_z P-slices at staging; rsp row-sums ===============
__global__ __launch_bounds__(256)
void k_agg(const float* __restrict__ W, const float* __restrict__ P,
           float* __restrict__ Q, float* __restrict__ rsp) {
    __shared__ float Ast[16][68];
    __shared__ float Bs[16][64];
    int t = threadIdx.x;
    int tx4 = (t & 15) * 4, ty4 = (t >> 4) * 4;
    int row0 = blockIdx.y * 64, col0 = blockIdx.x * 64;
    int kbase = blockIdx.z * 112;
    int ar = t >> 2, ak = (t & 3) * 4;
    int bk = t >> 4, bn = (t & 15) * 4;
    float acc[4][4] = {};
    float rowSum = 0.f;
    int gr_a = row0 + ar;

    for (int kb = kbase; kb < kbase + 112; kb += 16) {
        {
            float4 v = make_float4(0.f, 0.f, 0.f, 0.f);
            if (gr_a < N_NODES)
                v = *(const float4*)(W + (size_t)gr_a * WK + kb + ak);
            rowSum += v.x + v.y + v.z + v.w;
            Ast[ak + 0][ar] = v.x; Ast[ak + 1][ar] = v.y;
            Ast[ak + 2][ar] = v.z; Ast[ak + 3][ar] = v.w;
        }
        {   // B tile row (kb+bk) = sum of 8 interleaved P slices (pad rows pre-zeroed)
            size_t pb = (size_t)(kb + bk) * ZF * DIM + col0 + bn;
            float4 b = *(const float4*)(P + pb);
            #pragma unroll
            for (int zz = 1; zz < ZF; zz++) {
                float4 b2 = *(const float4*)(P + pb + (size_t)zz * DIM);
                b.x += b2.x; b.y += b2.y; b.z += b2.z; b.w += b2.w;
            }
            *(float4*)&Bs[bk][bn] = b;
        }
        __syncthreads();
        #pragma unroll
        for (int kk = 0; kk < 16; kk++) {
            float4 a = *(const float4*)&Ast[kk][ty4];
            float4 b = *(const float4*)&Bs[kk][tx4];
            acc[0][0] += a.x*b.x; acc[0][1] += a.x*b.y; acc[0][2] += a.x*b.z; acc[0][3] += a.x*b.w;
            acc[1][0] += a.y*b.x; acc[1][1] += a.y*b.y; acc[1][2] += a.y*b.z; acc[1][3] += a.y*b.w;
            acc[2][0] += a.z*b.x; acc[2][1] += a.z*b.y; acc[2][2] += a.z*b.z; acc[2][3] += a.z*b.w;
            acc[3][0] += a.w*b.x; acc[3][1] += a.w*b.y; acc[3][2] += a.w*b.z; acc[3][3] += a.w*b.w;
        }
        __syncthreads();
    }

    // per-k-chunk W row-sum partial -> rsp[bz][row]  (plain store, bx==0 writes)
    rowSum += __shfl_xor(rowSum, 1);
    rowSum += __shfl_xor(rowSum, 2);
    if (blockIdx.x == 0 && (t & 3) == 0 && gr_a < N_NODES)
        rsp[blockIdx.z * RSP + gr_a] = rowSum;

    #pragma unroll
    for (int i = 0; i < 4; i++) {
        int gr = row0 + ty4 + i;
        if (gr < N_NODES)
            *(float4*)&Q[((size_t)gr * ZA + blockIdx.z) * DIM + col0 + tx4] =
                make_float4(acc[i][0], acc[i][1], acc[i][2], acc[i][3]);
    }
}

// =============== final: act(sum_z Q) viewed as (512,650) @ fc_w + fc_b -> sigmoid ===============
__global__ void k_final(const float* __restrict__ Q, const float* __restrict__ rsp,
                        const float* __restrict__ bias,
                        const float* __restrict__ fcw, const float* __restrict__ fcb,
                        float* __restrict__ out) {
    int b = blockIdx.x * 4 + (threadIdx.x >> 6);
    int lane = threadIdx.x & 63;
    if (b >= 512) return;
    float s = 0.f;
    for (int i = lane; i < N_NODES; i += 64) {
        int j = b * N_NODES + i;
        int r = j >> 9, c = j & 511;             // storage is (650,512) row-major
        float q = 0.f, rsum = 0.f;
        #pragma unroll
        for (int zz = 0; zz < ZA; zz++) {
            q    += Q[((size_t)r * ZA + zz) * DIM + c];
            rsum += rsp[zz * RSP + r];
        }
        float v = fmaf(q, 1.f / (rsum + 1e-16f), bias[c]);
        v = v > 0.f ? v : 0.01f * v;
        s += v * fcw[i];
    }
    #pragma unroll
    for (int o = 32; o > 0; o >>= 1) s += __shfl_down(s, o);
    if (lane == 0) out[b] = 1.f / (1.f + expf(-(s + fcb[0])));
}

extern "C" void kernel_launch(void* const* d_in, const int* in_sizes, int n_in,
                              void* d_out, int out_size, void* d_ws, size_t ws_size,
                              hipStream_t stream) {
    const float* x_s   = (const float*)d_in[0];
    const float* x_t   = (const float*)d_in[1];
    const int*   ei    = (const int*)d_in[2];
    const float* W1    = (const float*)d_in[5];
    const float* asrc1 = (const float*)d_in[6];
    const float* adst1 = (const float*)d_in[7];
    const float* b1    = (const float*)d_in[8];
    const float* W4    = (const float*)d_in[9];
    const float* asrc4 = (const float*)d_in[10];
    const float* adst4 = (const float*)d_in[11];
    const float* b4    = (const float*)d_in[12];
    const float* fcw   = (const float*)d_in[13];
    const float* fcb   = (const float*)d_in[14];
    float* out = (float*)d_out;

    // layout: [ P (672x8x512) | W1d | W2d | Q (650x6x512) | alsp | aldp | rsp1 | rsp2 ]
    // one memset zeroes: P pad rows (650..671, contiguous tail of P) + W1d + W2d
    float* ws   = (float*)d_ws;
    float* P    = ws;                                    // WK*ZF*DIM = 2,752,512
    float* W1d  = P + (size_t)WK * ZF * DIM;             // 650*672
    float* W2d  = W1d + (size_t)N_NODES * WK;            // 650*672
    float* Q    = W2d + (size_t)N_NODES * WK;            // 650*6*512
    float* alsp = Q + (size_t)N_NODES * ZA * DIM;        // 650*64
    float* aldp = alsp + N_NODES * 64;                   // 650*64
    float* rsp1 = aldp + N_NODES * 64;                   // 6*656
    float* rsp2 = rsp1 + ZA * RSP;                       // 6*656

    float* zbeg = P + (size_t)N_NODES * ZF * DIM;
    size_t zbytes = (size_t)((WK - N_NODES) * ZF * DIM   // P pad rows 650..671
                           + 2 * N_NODES * WK)           // W1d, W2d
                    * sizeof(float);
    hipMemsetAsync(zbeg, 0, zbytes, stream);

    dim3 gF(DIM / 64, (N_NODES + 63) / 64, ZF);          // 8 x 11 x 8 = 704 blocks
    dim3 gA(DIM / 64, (N_NODES + 63) / 64, ZA);          // 8 x 11 x 6 = 528 blocks

    // ---- layer 1 ----
    k_feat<<<gF, 256, 0, stream>>>(x_s, x_t, W1, asrc1, adst1,
                                   nullptr, nullptr, nullptr, P, alsp, aldp, 1);
    k_build<<<128, 256, 0, stream>>>(ei, alsp, aldp, W1d);
    k_agg<<<gA, 256, 0, stream>>>(W1d, P, Q, rsp1);

    // ---- layer 2 (layer-1 normalize/bias/relu fused into A-staging) ----
    k_feat<<<gF, 256, 0, stream>>>(nullptr, nullptr, W4, asrc4, adst4,
                                   Q, rsp1, b1, P, alsp, aldp, 3);
    k_build<<<128, 256, 0, stream>>>(ei, alsp, aldp, W2d);
    k_agg<<<gA, 256, 0, stream>>>(W2d, P, Q, rsp2);

    // ---- final (layer-2 normalize/bias/leaky fused into load) ----
    k_final<<<128, 256, 0, stream>>>(Q, rsp2, b4, fcw, fcb, out);
}